// Round 7
// baseline (338.614 us; speedup 1.0000x reference)
//
#include <hip/hip_runtime.h>
#include <hip/hip_bf16.h>

// B=4, S=2048, E=1024, H=16, D=64
#define PB 4
#define PS 2048
#define PH 16
#define PD 64
#define PE 1024

typedef short v8s __attribute__((ext_vector_type(8)));
typedef float v4f __attribute__((ext_vector_type(4)));

__device__ __forceinline__ ushort f2b(float f) {
  union { __hip_bfloat16 b; ushort u; } cv;
  cv.b = __float2bfloat16(f);
  return cv.u;
}

// async 16B global->LDS (direct DMA, no VGPR round trip)
__device__ __forceinline__ void cp16(const __hip_bfloat16* g, __hip_bfloat16* l) {
  __builtin_amdgcn_global_load_lds(
      (const __attribute__((address_space(1))) void*)g,
      (__attribute__((address_space(3))) void*)l, 16, 0, 0);
}

// ---------------------------------------------------------------------------
// Prep kernels: fp32 -> bf16 convert / transpose (memory-bound)
// ---------------------------------------------------------------------------
__global__ __launch_bounds__(256) void conv_f2b(const float* __restrict__ S,
                                                __hip_bfloat16* __restrict__ D) {
  int i = blockIdx.x * 256 + threadIdx.x;
  float4 f = reinterpret_cast<const float4*>(S)[i];
  union { ushort u[4]; uint2 v; } pk;
  pk.u[0] = f2b(f.x); pk.u[1] = f2b(f.y); pk.u[2] = f2b(f.z); pk.u[3] = f2b(f.w);
  reinterpret_cast<uint2*>(D)[i] = pk.v;
}

// S [R][C] fp32 -> D [C][R] bf16
__global__ __launch_bounds__(256) void transp_f2b(const float* __restrict__ S,
                                                  __hip_bfloat16* __restrict__ D,
                                                  int R, int C) {
  __shared__ float tile[32][33];
  const int t = threadIdx.x;
  const int tx = t & 31, ty = t >> 5;
  const int r0 = blockIdx.y * 32, c0 = blockIdx.x * 32;
#pragma unroll
  for (int i = 0; i < 4; ++i)
    tile[ty + 8 * i][tx] = S[(size_t)(r0 + ty + 8 * i) * C + c0 + tx];
  __syncthreads();
#pragma unroll
  for (int i = 0; i < 4; ++i)
    D[(size_t)(c0 + ty + 8 * i) * R + r0 + tx] = __float2bfloat16(tile[tx][ty + 8 * i]);
}

// ---------------------------------------------------------------------------
// MFMA GEMM v2: block tile 256x128, BK=64, 4 waves each 64x128 (4x8 MFMA
// blocks). LDS:MFMA cycle ratio ~0.93 (was 1.24 at 64x64 wave tile).
// XOR-swizzled LDS chunks, global_load_lds width-16 staging.
// MODE 0: QKV scatter epilogue; MODE 1: proj fp32 epilogue.
// ---------------------------------------------------------------------------
template <int MODE>
__global__ __launch_bounds__(256) void gemm_bt(
    const __hip_bfloat16* __restrict__ A, const __hip_bfloat16* __restrict__ BT,
    const float* __restrict__ bias, void* __restrict__ outv) {
  __shared__ __hip_bfloat16 As[256 * 64];
  __shared__ __hip_bfloat16 Bs[128 * 64];
  const int t = threadIdx.x;
  const int lane = t & 63, w = t >> 6;
  const int ln = lane & 15, qd = lane >> 4;
  const int m0 = blockIdx.y * 256, n0 = blockIdx.x * 128;
  v4f acc[4][8] = {};

  for (int k0 = 0; k0 < PE; k0 += 64) {
    __syncthreads();
#pragma unroll
    for (int i = 0; i < 8; ++i) {
      int idx = t + 256 * i;           // 0..2047 16B slots (A: 256 rows x 8)
      int r = idx >> 3, cs = idx & 7;
      int cg = cs ^ (r & 7);
      cp16(A + (size_t)(m0 + r) * PE + k0 + cg * 8, As + idx * 8);
    }
#pragma unroll
    for (int i = 0; i < 4; ++i) {
      int idx = t + 256 * i;           // 0..1023 (B: 128 rows x 8)
      int r = idx >> 3, cs = idx & 7;
      int cg = cs ^ (r & 7);
      cp16(BT + (size_t)(n0 + r) * PE + k0 + cg * 8, Bs + idx * 8);
    }
    __syncthreads();
#pragma unroll
    for (int kk = 0; kk < 2; ++kk) {
      v8s af[4], bf[8];
#pragma unroll
      for (int mb = 0; mb < 4; ++mb) {
        int ra = w * 64 + mb * 16 + ln;
        int ca = (kk * 4 + qd) ^ (ra & 7);
        af[mb] = *reinterpret_cast<const v8s*>(As + ra * 64 + ca * 8);
      }
#pragma unroll
      for (int nb = 0; nb < 8; ++nb) {
        int rb = nb * 16 + ln;
        int cb = (kk * 4 + qd) ^ (rb & 7);
        bf[nb] = *reinterpret_cast<const v8s*>(Bs + rb * 64 + cb * 8);
      }
#pragma unroll
      for (int mb = 0; mb < 4; ++mb)
#pragma unroll
        for (int nb = 0; nb < 8; ++nb)
          acc[mb][nb] = __builtin_amdgcn_mfma_f32_16x16x32_bf16(af[mb], bf[nb],
                                                                acc[mb][nb], 0, 0, 0);
    }
  }

  // epilogue: C row = m0 + w*64 + mb*16 + qd*4 + i, col = n0 + nb*16 + ln
  const int mwb = m0 + w * 64 + qd * 4;
  const int nwb = n0 + ln;
  if (MODE == 0) {
    __hip_bfloat16* QKV = (__hip_bfloat16*)outv;
#pragma unroll
    for (int nb = 0; nb < 8; ++nb) {
      int n = nwb + nb * 16;
      float bv = bias[n];
      int which = n >> 10, h = (n >> 6) & 15, d = n & 63;
#pragma unroll
      for (int mb = 0; mb < 4; ++mb) {
        int r0 = mwb + mb * 16;
        int b = r0 >> 11, s0 = r0 & (PS - 1);
        v4f a = acc[mb][nb];
        if (which == 2) {
          // V stored [b,h,d,s]: 4 consecutive s -> one 8B store
          union { ushort u[4]; uint2 v; } pk;
#pragma unroll
          for (int i = 0; i < 4; ++i) pk.u[i] = f2b(a[i] + bv);
          size_t idx = (((size_t)(2 * PB + b) * PH + h) * PD + d) * PS + s0;
          *reinterpret_cast<uint2*>(&QKV[idx]) = pk.v;
        } else {
          float sc = (which == 0) ? 0.125f : 1.0f;
          size_t base = (((size_t)(which * PB + b) * PH + h) * PS + s0) * PD + d;
#pragma unroll
          for (int i = 0; i < 4; ++i)
            QKV[base + (size_t)i * PD] = __float2bfloat16((a[i] + bv) * sc);
        }
      }
    }
  } else {
    float* Co = (float*)outv;
#pragma unroll
    for (int nb = 0; nb < 8; ++nb) {
      int n = nwb + nb * 16;
      float bv = bias[n];
#pragma unroll
      for (int mb = 0; mb < 4; ++mb) {
        int r0 = mwb + mb * 16;
        v4f a = acc[mb][nb];
#pragma unroll
        for (int i = 0; i < 4; ++i)
          Co[(size_t)(r0 + i) * PE + n] = a[i] + bv;
      }
    }
  }
}

// ---------------------------------------------------------------------------
// MFMA flash attention v3.1: 128 Q-rows/block (wave = 32 rows = 2 sub-blocks),
// 128-key tiles, S^T trick (A=K, B=Q) -> packed b64 P-stores, wave-private P
// (no P barrier), no-max softmax, K-frag reads hoisted out of sub-block loop.
// QKV bf16: Q/K [b,h,s,d], V [b,h,d,s]. O bf16 [b,s,h,d]. Q pre-scaled 0.125.
// ---------------------------------------------------------------------------
__global__ __launch_bounds__(256) void attn_mfma3(
    const __hip_bfloat16* __restrict__ QKV, __hip_bfloat16* __restrict__ O) {
  __shared__ __hip_bfloat16 Ks[128 * 64];   // [key][d], XOR-swizzled chunks
  __shared__ __hip_bfloat16 Vts[64 * 128];  // [d][key], XOR-swizzled chunks
  __shared__ __hip_bfloat16 Ps[128][136];   // [q_local][key], padded
  const int t = threadIdx.x;
  const int lane = t & 63, w = t >> 6;
  const int ln = lane & 15, qd = lane >> 4;
  const int b = blockIdx.y >> 4, h = blockIdx.y & 15;
  const int q0 = blockIdx.x * 128;
  const __hip_bfloat16* Qb = QKV + (size_t)(b * PH + h) * PS * PD;
  const __hip_bfloat16* Kb = QKV + (size_t)((PB + b) * PH + h) * PS * PD;
  const __hip_bfloat16* Vb = QKV + (size_t)((2 * PB + b) * PH + h) * PD * PS;

  // Q B-frags: wave w owns q-rows q0+32w .. +31 (two 16-row sub-blocks u)
  v8s qf[2][2];
#pragma unroll
  for (int u = 0; u < 2; ++u) {
    size_t qr = (size_t)(q0 + 32 * w + 16 * u + ln) * PD;
    qf[u][0] = *reinterpret_cast<const v8s*>(Qb + qr + qd * 8);
    qf[u][1] = *reinterpret_cast<const v8s*>(Qb + qr + 32 + qd * 8);
  }
  v4f oacc[2][4] = {};
  float lrow[2] = {0.f, 0.f};

  for (int kt = 0; kt < PS; kt += 128) {
    __syncthreads();  // prior K/V frag reads done
#pragma unroll
    for (int i = 0; i < 4; ++i) {
      int idx = t + 256 * i;  // 0..1023 16B slots
      int rk = idx >> 3, ck = (idx & 7) ^ (rk & 7);
      cp16(Kb + (size_t)(kt + rk) * PD + ck * 8, Ks + idx * 8);
      int rv = idx >> 4, cv = (idx & 15) ^ (rv & 7);
      cp16(Vb + (size_t)rv * PS + kt + cv * 8, Vts + idx * 8);
    }
    __syncthreads();

    // K frags once (shared by both sub-blocks)
    v8s kf[8][2];
#pragma unroll
    for (int nb = 0; nb < 8; ++nb) {
      int nr = nb * 16 + ln;
      int c0 = qd ^ (nr & 7);
      kf[nb][0] = *reinterpret_cast<const v8s*>(Ks + nr * 64 + c0 * 8);
      kf[nb][1] = *reinterpret_cast<const v8s*>(Ks + nr * 64 + (c0 ^ 4) * 8);
    }
    // S^T = K Q^T per sub-block; exp; packed P store (wave-private rows)
#pragma unroll
    for (int u = 0; u < 2; ++u) {
      float psum = 0.f;
#pragma unroll
      for (int nb = 0; nb < 8; ++nb) {
        v4f z = {};
        z = __builtin_amdgcn_mfma_f32_16x16x32_bf16(kf[nb][0], qf[u][0], z, 0, 0, 0);
        v4f sv = __builtin_amdgcn_mfma_f32_16x16x32_bf16(kf[nb][1], qf[u][1], z, 0, 0, 0);
        // lane holds keys nb*16+qd*4+i of q = 32w+16u+ln
        union { ushort pu[4]; uint2 pv; } pk;
#pragma unroll
        for (int i = 0; i < 4; ++i) {
          float p = __expf(sv[i]);
          psum += p;
          pk.pu[i] = f2b(p);
        }
        *reinterpret_cast<uint2*>(&Ps[32 * w + 16 * u + ln][nb * 16 + qd * 4]) = pk.pv;
      }
      // reduce over qd lane-groups (lane bits 4,5)
      psum += __shfl_xor(psum, 16);
      psum += __shfl_xor(psum, 32);
      lrow[u] += psum;
    }
    // P A-frags (own wave's rows; same-wave LDS ops are in-order)
    v8s pf[2][4];
#pragma unroll
    for (int u = 0; u < 2; ++u)
#pragma unroll
      for (int s = 0; s < 4; ++s)
        pf[u][s] = *reinterpret_cast<const v8s*>(
            &Ps[32 * w + 16 * u + ln][s * 32 + qd * 8]);
    // O += P V  (V-frags shared across both sub-blocks)
#pragma unroll
    for (int db = 0; db < 4; ++db) {
      int rv = db * 16 + ln;
      v4f o0 = oacc[0][db], o1 = oacc[1][db];
#pragma unroll
      for (int s = 0; s < 4; ++s) {
        int cv = (s * 4 + qd) ^ (rv & 7);
        v8s vf = *reinterpret_cast<const v8s*>(Vts + rv * 128 + cv * 8);
        o0 = __builtin_amdgcn_mfma_f32_16x16x32_bf16(pf[0][s], vf, o0, 0, 0, 0);
        o1 = __builtin_amdgcn_mfma_f32_16x16x32_bf16(pf[1][s], vf, o1, 0, 0, 0);
      }
      oacc[0][db] = o0;
      oacc[1][db] = o1;
    }
  }
  // epilogue: redistribute lrow (indexed by q=ln) to O C-layout (q=qd*4+i)
#pragma unroll
  for (int u = 0; u < 2; ++u) {
#pragma unroll
    for (int i = 0; i < 4; ++i) {
      float inv = 1.f / __shfl(lrow[u], qd * 4 + i);
      int sg = q0 + 32 * w + 16 * u + qd * 4 + i;
      size_t base = (((size_t)b * PS + sg) * PH + h) * PD;
#pragma unroll
      for (int db = 0; db < 4; ++db)
        O[base + db * 16 + ln] = __float2bfloat16(oacc[u][db][i] * inv);
    }
  }
}

// ---------------------------------------------------------------------------
// Legacy fp32-input GEMM (small-ws fallback)
// ---------------------------------------------------------------------------
__device__ __forceinline__ uint2 load4bf(const float* p) {
  const float4 f = *reinterpret_cast<const float4*>(p);
  union { ushort u[4]; uint2 v; } pk;
  pk.u[0] = f2b(f.x); pk.u[1] = f2b(f.y); pk.u[2] = f2b(f.z); pk.u[3] = f2b(f.w);
  return pk.v;
}
__device__ __forceinline__ uint2 load4bf(const __hip_bfloat16* p) {
  return *reinterpret_cast<const uint2*>(p);
}

template <typename AT, int MODE>
__global__ __launch_bounds__(256) void gemm128(
    const AT* __restrict__ A, const float* __restrict__ Bm,
    const float* __restrict__ bias, void* __restrict__ outv, int ldb) {
  __shared__ __hip_bfloat16 As[128][40];
  __shared__ __hip_bfloat16 Bs[128][40];
  const int t = threadIdx.x;
  const int lane = t & 63, w = t >> 6;
  const int ln = lane & 15, qd = lane >> 4;
  const int wm = w >> 1, wn = w & 1;
  const int m0 = blockIdx.y * 128, n0 = blockIdx.x * 128;
  v4f acc[4][4] = {};
  for (int k0 = 0; k0 < PE; k0 += 32) {
    __syncthreads();
#pragma unroll
    for (int i = 0; i < 4; ++i) {
      int p = t + 256 * i;
      int m = p >> 3, kc = p & 7;
      *reinterpret_cast<uint2*>(&As[m][kc * 4]) =
          load4bf(A + (size_t)(m0 + m) * PE + k0 + kc * 4);
    }
#pragma unroll
    for (int i = 0; i < 4; ++i) {
      int p = t + 256 * i;
      int n = p & 127, kc = p >> 7;
      union { ushort u[4]; uint2 v; } pk;
#pragma unroll
      for (int r = 0; r < 4; ++r)
        pk.u[r] = f2b(Bm[(size_t)(k0 + kc * 4 + r) * ldb + n0 + n]);
      *reinterpret_cast<uint2*>(&Bs[n][kc * 4]) = pk.v;
    }
    __syncthreads();
    v8s af[4], bf[4];
#pragma unroll
    for (int mb = 0; mb < 4; ++mb)
      af[mb] = *reinterpret_cast<const v8s*>(&As[wm * 64 + mb * 16 + ln][qd * 8]);
#pragma unroll
    for (int nb = 0; nb < 4; ++nb)
      bf[nb] = *reinterpret_cast<const v8s*>(&Bs[wn * 64 + nb * 16 + ln][qd * 8]);
#pragma unroll
    for (int mb = 0; mb < 4; ++mb)
#pragma unroll
      for (int nb = 0; nb < 4; ++nb)
        acc[mb][nb] = __builtin_amdgcn_mfma_f32_16x16x32_bf16(af[mb], bf[nb],
                                                              acc[mb][nb], 0, 0, 0);
  }
  const int mwb = m0 + wm * 64 + qd * 4;
  const int nwb = n0 + wn * 64 + ln;
  if (MODE == 0) {
    __hip_bfloat16* QKV = (__hip_bfloat16*)outv;
#pragma unroll
    for (int nb = 0; nb < 4; ++nb) {
      int n = nwb + nb * 16;
      float bv = bias[n];
      int which = n >> 10, h = (n >> 6) & 15, d = n & 63;
#pragma unroll
      for (int mb = 0; mb < 4; ++mb) {
        int r0 = mwb + mb * 16;
        int b = r0 >> 11, s0 = r0 & (PS - 1);
        v4f a = acc[mb][nb];
        if (which == 2) {
          union { ushort u[4]; uint2 v; } pk;
#pragma unroll
          for (int i = 0; i < 4; ++i) pk.u[i] = f2b(a[i] + bv);
          size_t idx = (((size_t)(2 * PB + b) * PH + h) * PD + d) * PS + s0;
          *reinterpret_cast<uint2*>(&QKV[idx]) = pk.v;
        } else {
          float sc = (which == 0) ? 0.125f : 1.0f;
          size_t base = (((size_t)(which * PB + b) * PH + h) * PS + s0) * PD + d;
#pragma unroll
          for (int i = 0; i < 4; ++i)
            QKV[base + (size_t)i * PD] = __float2bfloat16((a[i] + bv) * sc);
        }
      }
    }
  } else {
    float* Co = (float*)outv;
#pragma unroll
    for (int nb = 0; nb < 4; ++nb) {
      int n = nwb + nb * 16;
      float bv = bias[n];
#pragma unroll
      for (int mb = 0; mb < 4; ++mb) {
        int r0 = mwb + mb * 16;
        v4f a = acc[mb][nb];
#pragma unroll
        for (int i = 0; i < 4; ++i)
          Co[(size_t)(r0 + i) * PE + n] = a[i] + bv;
      }
    }
  }
}

// ---------------------------------------------------------------------------
extern "C" void kernel_launch(void* const* d_in, const int* in_sizes, int n_in,
                              void* d_out, int out_size, void* d_ws,
                              size_t ws_size, hipStream_t stream) {
  const float* x = (const float*)d_in[0];
  const float* w_qkv = (const float*)d_in[1];
  const float* b_qkv = (const float*)d_in[2];
  const float* w_proj = (const float*)d_in[3];
  const float* b_proj = (const float*)d_in[4];
  float* out = (float*)d_out;

  const size_t xE = (size_t)PB * PS * PE;             // 8,388,608
  const size_t wqE = (size_t)PE * 3 * PE;             // 3,145,728
  const size_t wpE = (size_t)PE * PE;                 // 1,048,576
  const size_t qkvE = (size_t)3 * PB * PH * PS * PD;  // 25,165,824
  const size_t needMain = (xE + wqE + wpE + qkvE) * 2;  // 75,497,472 B

  dim3 blk(256);
  dim3 gq(24, 32), ga(16, 64), gp(8, 32);

  if (ws_size >= needMain) {
    __hip_bfloat16* xb = (__hip_bfloat16*)d_ws;
    __hip_bfloat16* wqkvT = xb + xE;
    __hip_bfloat16* wprojT = wqkvT + wqE;
    __hip_bfloat16* qkv = wprojT + wpE;
    __hip_bfloat16* o = xb;  // xb dead after qkv gemm

    conv_f2b<<<dim3(xE / 1024), blk, 0, stream>>>(x, xb);
    transp_f2b<<<dim3(96, 32), blk, 0, stream>>>(w_qkv, wqkvT, PE, 3 * PE);
    transp_f2b<<<dim3(32, 32), blk, 0, stream>>>(w_proj, wprojT, PE, PE);
    gemm_bt<0><<<gq, blk, 0, stream>>>(xb, wqkvT, b_qkv, qkv);
    attn_mfma3<<<ga, blk, 0, stream>>>(qkv, o);
    gemm_bt<1><<<gp, blk, 0, stream>>>(o, wprojT, b_proj, out);
  } else {
    // legacy small-ws path
    __hip_bfloat16* qkv = (__hip_bfloat16*)d_ws;
    dim3 gq128(24, 64), gp128(8, 64);
    if (ws_size >= (qkvE + xE) * 2) {
      __hip_bfloat16* o = qkv + qkvE;
      gemm128<float, 0><<<gq128, blk, 0, stream>>>(x, w_qkv, b_qkv, qkv, 3 * PE);
      attn_mfma3<<<ga, blk, 0, stream>>>(qkv, o);
      gemm128<__hip_bfloat16, 1><<<gp128, blk, 0, stream>>>(o, w_proj, b_proj, out, PE);
    } else {
      __hip_bfloat16* o = (__hip_bfloat16*)d_out;
      float* tmp = (float*)d_ws;
      gemm128<float, 0><<<gq128, blk, 0, stream>>>(x, w_qkv, b_qkv, qkv, 3 * PE);
      attn_mfma3<<<ga, blk, 0, stream>>>(qkv, o);
      gemm128<__hip_bfloat16, 1><<<gp128, blk, 0, stream>>>(o, w_proj, b_proj, tmp, PE);
      hipMemcpyAsync(d_out, tmp, xE * sizeof(float), hipMemcpyDeviceToDevice, stream);
    }
  }
}